// Round 5
// baseline (688.018 us; speedup 1.0000x reference)
//
#include <hip/hip_runtime.h>
#include <cstdint>
#include <cstddef>

// All external tensors are FP32 (per reference). Internals use bf16 for MFMA.
typedef unsigned short u16;
typedef __attribute__((ext_vector_type(4))) float f32x4;
typedef __attribute__((ext_vector_type(8))) __bf16 bf16x8;
typedef __attribute__((ext_vector_type(4))) __bf16 bf16x4;
typedef __attribute__((ext_vector_type(8))) unsigned short u16x8;
typedef __attribute__((ext_vector_type(4))) unsigned short u16x4;

#define DEV static __device__ __forceinline__

#if __has_builtin(__builtin_amdgcn_exp2f)
#define EXP2(x) __builtin_amdgcn_exp2f(x)
#else
#define EXP2(x) exp2f(x)
#endif

DEV float bf2f(u16 v) { return __uint_as_float(((unsigned)v) << 16); }
DEV u16 f2bf(float f) {
  unsigned u = __float_as_uint(f);
  return (u16)((u + 0x7FFFu + ((u >> 16) & 1u)) >> 16);
}

DEV void gl_lds16(const void* g, void* l) {
  __builtin_amdgcn_global_load_lds((const __attribute__((address_space(1))) void*)g,
                                   (__attribute__((address_space(3))) void*)l, 16, 0, 0);
}

// ---------------------------------------------------------------------------
// 64x64 tiled transpose + fp32->bf16 cast: out[c][r] = bf16(in[r][c]).
__global__ __launch_bounds__(256) void transpose64(const float* __restrict__ in,
                                                   u16* __restrict__ out, int incols) {
  __shared__ __attribute__((aligned(16))) u16 t[64 * 72];
  const int r0 = blockIdx.x * 64, c0 = blockIdx.y * 64, tid = threadIdx.x;
#pragma unroll
  for (int i = 0; i < 2; i++) {
    int c = i * 256 + tid;
    int row = c >> 3, cc = c & 7;
    const float* src = &in[(size_t)(r0 + row) * incols + c0 + cc * 8];
    f32x4 v0 = *(const f32x4*)src;
    f32x4 v1 = *(const f32x4*)(src + 4);
    u16x8 o;
#pragma unroll
    for (int j = 0; j < 4; j++) { o[j] = f2bf(v0[j]); o[4 + j] = f2bf(v1[j]); }
    *(u16x8*)&t[row * 72 + cc * 8] = o;
  }
  __syncthreads();
#pragma unroll
  for (int i = 0; i < 2; i++) {
    int c = i * 256 + tid;
    int d = c >> 3, nc = c & 7;
    u16x8 o;
#pragma unroll
    for (int j = 0; j < 8; j++) o[j] = t[(nc * 8 + j) * 72 + d];
    *(u16x8*)&out[(size_t)(c0 + d) * 1024 + r0 + nc * 8] = o;
  }
}

// ---------------------------------------------------------------------------
// LayerNorm over DIM=1024 (fp32 in, bf16 out), one block per row.
__global__ __launch_bounds__(256) void ln_x(const float* __restrict__ x,
                                            const float* __restrict__ sc,
                                            const float* __restrict__ bi,
                                            u16* __restrict__ xn) {
  __shared__ float red[8];
  const int row = blockIdx.x, tid = threadIdx.x;
  const int w = tid >> 6;
  f32x4 f = *(const f32x4*)&x[(size_t)row * 1024 + tid * 4];
  float s = f[0] + f[1] + f[2] + f[3];
  float q = f[0] * f[0] + f[1] * f[1] + f[2] * f[2] + f[3] * f[3];
#pragma unroll
  for (int off = 1; off < 64; off <<= 1) {
    s += __shfl_xor(s, off);
    q += __shfl_xor(q, off);
  }
  if ((tid & 63) == 0) { red[w] = s; red[4 + w] = q; }
  __syncthreads();
  float S = red[0] + red[1] + red[2] + red[3];
  float Q = red[4] + red[5] + red[6] + red[7];
  float mu = S * (1.0f / 1024.0f);
  float var = Q * (1.0f / 1024.0f) - mu * mu;
  float rs = rsqrtf(var + 1e-6f);
  f32x4 scv = *(const f32x4*)&sc[tid * 4];
  f32x4 biv = *(const f32x4*)&bi[tid * 4];
  u16* o = xn + (size_t)row * 1024 + tid * 4;
#pragma unroll
  for (int j = 0; j < 4; j++) o[j] = f2bf((f[j] - mu) * rs * scv[j] + biv[j]);
}

// ---------------------------------------------------------------------------
// C[M][N] = A[M][K] * Bt[N][K]^T, bf16 in; out bf16 or fp32 (F32OUT).
// 128x128 tile, BK=64 (half the barriers of BK=32), XOR-swizzled LDS
// (logical 16B chunk c of row r lives at slot c^(r&7)) -> <=2-way conflicts.
template <bool F32OUT>
__global__ __launch_bounds__(256) void gemm_bt(const u16* __restrict__ A,
                                               const u16* __restrict__ Bt,
                                               void* __restrict__ Cp,
                                               int M, int N, int K) {
  __shared__ __attribute__((aligned(16))) u16 Als[128 * 64];
  __shared__ __attribute__((aligned(16))) u16 Bls[128 * 64];
  const int tid = threadIdx.x;
  const int w = tid >> 6, lane = tid & 63, ln = lane & 15, quad = lane >> 4;
  const int m0 = blockIdx.y * 128, n0 = blockIdx.x * 128;
  const int moff = (w & 1) * 64, noff = (w >> 1) * 64;
  const f32x4 fzero = {0.f, 0.f, 0.f, 0.f};
  f32x4 acc[4][4];
#pragma unroll
  for (int i = 0; i < 4; i++)
#pragma unroll
    for (int j = 0; j < 4; j++) acc[i][j] = fzero;

  // staging source bases: 4 chunks each for A and B per thread
  const u16* aS[4];
  const u16* bS[4];
#pragma unroll
  for (int i = 0; i < 4; i++) {
    int s = i * 256 + tid;
    int row = s >> 3, cs = (s & 7) ^ (row & 7);
    aS[i] = A + (size_t)(m0 + row) * K + cs * 8;
    bS[i] = Bt + (size_t)(n0 + row) * K + cs * 8;
  }

  for (int k0 = 0; k0 < K; k0 += 64) {
    __syncthreads();
#pragma unroll
    for (int i = 0; i < 4; i++) {
      int s = i * 256 + tid;
      gl_lds16(aS[i] + k0, &Als[s * 8]);
      gl_lds16(bS[i] + k0, &Bls[s * 8]);
    }
    __syncthreads();
#pragma unroll
    for (int kk = 0; kk < 2; kk++) {
      bf16x8 af[4], bfv[4];
#pragma unroll
      for (int mi = 0; mi < 4; mi++)
        af[mi] = *(const bf16x8*)
            &Als[(moff + mi * 16 + ln) * 64 + (((kk * 4 + quad) ^ (ln & 7)) * 8)];
#pragma unroll
      for (int ni = 0; ni < 4; ni++)
        bfv[ni] = *(const bf16x8*)
            &Bls[(noff + ni * 16 + ln) * 64 + (((kk * 4 + quad) ^ (ln & 7)) * 8)];
#pragma unroll
      for (int mi = 0; mi < 4; mi++)
#pragma unroll
        for (int ni = 0; ni < 4; ni++)
          acc[mi][ni] = __builtin_amdgcn_mfma_f32_16x16x32_bf16(af[mi], bfv[ni],
                                                                acc[mi][ni], 0, 0, 0);
    }
  }
#pragma unroll
  for (int mi = 0; mi < 4; mi++)
#pragma unroll
    for (int ni = 0; ni < 4; ni++)
#pragma unroll
      for (int r = 0; r < 4; r++) {
        size_t m = m0 + moff + mi * 16 + quad * 4 + r;
        size_t n = n0 + noff + ni * 16 + ln;
        if (F32OUT)
          ((float*)Cp)[m * N + n] = acc[mi][ni][r];
        else
          ((u16*)Cp)[m * N + n] = f2bf(acc[mi][ni][r]);
      }
}

// ---------------------------------------------------------------------------
// Per-head LN of q and k slices of qkv[8192][1536] (bf16); fp32 params.
// Q pre-scaled by 0.125*log2(e): scores directly in exp2 domain (fixed-max
// softmax is safe: LN'd q,k => |score| <= ~11.5).
__global__ __launch_bounds__(256) void qk_ln(const u16* __restrict__ qkv,
                                             const float* __restrict__ qs,
                                             const float* __restrict__ qb,
                                             const float* __restrict__ ks,
                                             const float* __restrict__ kb,
                                             u16* __restrict__ Q,
                                             u16* __restrict__ Kb) {
  const float SCL = 0.18033688011112042f;  // 0.125 * log2(e)
  const int m = blockIdx.x;
  const int b = m >> 11, n = m & 2047;
  const int tid = threadIdx.x, w = tid >> 6, lane = tid & 63;
  const u16* rowp = qkv + (size_t)m * 1536;
  const float qsc = qs[lane], qbi = qb[lane];
  const float ksc = ks[lane], kbi = kb[lane];
#pragma unroll
  for (int i = 0; i < 4; i++) {
    int h = w * 4 + i;
    float v = bf2f(rowp[h * 64 + lane]);
    float s = v, q2 = v * v;
#pragma unroll
    for (int off = 1; off < 64; off <<= 1) {
      s += __shfl_xor(s, off);
      q2 += __shfl_xor(q2, off);
    }
    float mu = s * (1.0f / 64.0f);
    float var = q2 * (1.0f / 64.0f) - mu * mu;
    float y = ((v - mu) * rsqrtf(var + 1e-6f) * qsc + qbi) * SCL;
    Q[((size_t)(b * 16 + h) * 2048 + n) * 64 + lane] = f2bf(y);
  }
  {
    int g = w;
    float v = bf2f(rowp[1024 + g * 64 + lane]);
    float s = v, q2 = v * v;
#pragma unroll
    for (int off = 1; off < 64; off <<= 1) {
      s += __shfl_xor(s, off);
      q2 += __shfl_xor(q2, off);
    }
    float mu = s * (1.0f / 64.0f);
    float var = q2 * (1.0f / 64.0f) - mu * mu;
    float y = (v - mu) * rsqrtf(var + 1e-6f) * ksc + kbi;
    Kb[((size_t)(b * 4 + g) * 2048 + n) * 64 + lane] = f2bf(y);
  }
}

// ---------------------------------------------------------------------------
// V transpose: qkv v-slice -> Vt [b][g][64][2048]. grid = (32, 16).
// Keys are PERMUTED within each 64-key tile so attn's PV A-operand is one
// contiguous 16B chunk per lane:
//   key kappa = 32c + quad*4 + u*16 + v  ->  pos p = 32c + quad*8 + u*4 + v
__global__ __launch_bounds__(256) void vtrans(const u16* __restrict__ qkv,
                                              u16* __restrict__ Vt) {
  __shared__ __attribute__((aligned(16))) u16 t[64 * 72];
  const int n0 = blockIdx.x * 64;
  const int bg = blockIdx.y;
  const int b = bg >> 2, g = bg & 3;
  const int tid = threadIdx.x;
  const u16* src = qkv + (size_t)(b * 2048 + n0) * 1536 + 1280 + g * 64;
#pragma unroll
  for (int i = 0; i < 2; i++) {
    int c = i * 256 + tid;
    int row = c >> 3, cc = c & 7;
    *(f32x4*)&t[row * 72 + cc * 8] = *(const f32x4*)&src[(size_t)row * 1536 + cc * 8];
  }
  __syncthreads();
  u16* dst = Vt + (size_t)bg * 64 * 2048 + n0;
#pragma unroll
  for (int i = 0; i < 2; i++) {
    int c = i * 256 + tid;
    int d = c >> 3, nc = c & 7;
    // keys kappa = nc*8 + j; j=0..3 land at pA+j, j=4..7 at pA+8+(j&3)
    const int pA = 32 * (nc >> 2) + (nc & 1) * 16 + ((nc >> 1) & 1) * 4;
    u16x8 o;
#pragma unroll
    for (int j = 0; j < 8; j++) o[j] = t[(nc * 8 + j) * 72 + d];
    u16x4 lo = {o[0], o[1], o[2], o[3]};
    u16x4 hi = {o[4], o[5], o[6], o[7]};
    *(u16x4*)&dst[(size_t)d * 2048 + pA] = lo;
    *(u16x4*)&dst[(size_t)d * 2048 + pA + 8] = hi;
  }
}

// ---------------------------------------------------------------------------
// Flash attention, transposed-S, fixed-max softmax, KT=64 keys/iter.
//
// Round-5: revert the round-4 no-LDS experiment (latency-bound disaster:
// depth-1 register prefetch cannot hide L2 latency, 8x VMEM inst amplif.).
// Back to round-3 structure (LDS K/V double-buffer, one barrier/kt,
// 64 q-rows/wave, lane-local P, permuted-V single-b128 PV reads, 0 bank
// conflicts) with DOUBLED CONCURRENCY: 4 waves/block (256 thr), block
// covers 256 q-rows, grid (8,64) = 512 blocks = exactly 2 blocks/CU x 4
// waves = 16 waves/CU = 4 waves/SIMD (round-3 had 2). Round-3's pipe
// ledger summed to ~98% serialized; more waves/SIMD lets one wave's exp2
// overlap another's MFMA/ds_read. Per-wave body is byte-identical to
// round-3 (compiled to exactly 128 VGPR = the 4-waves/SIMD cap).
__global__ __launch_bounds__(256, 4) void attn(const u16* __restrict__ Q,
                                               const u16* __restrict__ Kb,
                                               const u16* __restrict__ Vt,
                                               u16* __restrict__ Out) {
  __shared__ __attribute__((aligned(16))) u16 Kls0[64 * 64];
  __shared__ __attribute__((aligned(16))) u16 Kls1[64 * 64];
  __shared__ __attribute__((aligned(16))) u16 Vls0[64 * 64];
  __shared__ __attribute__((aligned(16))) u16 Vls1[64 * 64];
  const int qt = blockIdx.x;
  const int bh = blockIdx.y;
  const int b = bh >> 4, h = bh & 15, g = h >> 2;
  const int tid = threadIdx.x, w = tid >> 6, lane = tid & 63;
  const int ln = lane & 15, quad = lane >> 4;
  const u16* Qg = Q + ((size_t)(b * 16 + h) * 2048 + qt * 256 + w * 64) * 64;
  const u16* Kg = Kb + (size_t)(b * 4 + g) * 2048 * 64;
  const u16* Vg = Vt + (size_t)(b * 4 + g) * 64 * 2048;
  const f32x4 fzero = {0.f, 0.f, 0.f, 0.f};

  // Q fragments (B-operand): rows m = mi*16+ln, k(d) = ks2*32 + quad*8
  bf16x8 qf[4][2];
#pragma unroll
  for (int mi = 0; mi < 4; mi++)
#pragma unroll
    for (int ks2 = 0; ks2 < 2; ks2++)
      qf[mi][ks2] = *(const bf16x8*)&Qg[(size_t)(mi * 16 + ln) * 64 + ks2 * 32 + quad * 8];

  f32x4 oacc[4][4];  // [ni(d-tile)][mi(m-tile)]
#pragma unroll
  for (int ni = 0; ni < 4; ni++)
#pragma unroll
    for (int mi = 0; mi < 4; mi++) oacc[ni][mi] = fzero;
  float lacc[4] = {0.f, 0.f, 0.f, 0.f};  // per-lane partial row sums

  // staging geometry: 2 K-chunks + 2 V-chunks per thread (256 threads)
  int krow[2], kcs[2];
#pragma unroll
  for (int i = 0; i < 2; i++) {
    int s = i * 256 + tid;
    krow[i] = s >> 3;
    kcs[i] = (s & 7) ^ (krow[i] & 7);
  }

  auto STAGE = [&](int kt, u16* Kd, u16* Vd) {
#pragma unroll
    for (int i = 0; i < 2; i++) {
      int s = i * 256 + tid;
      gl_lds16(Kg + (size_t)(kt * 64 + krow[i]) * 64 + kcs[i] * 8, &Kd[s * 8]);
      gl_lds16(Vg + (size_t)krow[i] * 2048 + kt * 64 + kcs[i] * 8, &Vd[s * 8]);
    }
  };

  auto BODY = [&](int kt, const u16* K_, const u16* V_, u16* Kn, u16* Vn) {
    if (kt + 1 < 32) STAGE(kt + 1, Kn, Vn);  // prefetch, in flight during compute

#pragma unroll
    for (int c = 0; c < 2; c++) {  // two 32-key chunks
      // K fragments for keys c*32 + [0,32)
      bf16x8 kf[2][2];  // [ni(key-16-tile)][kstep(d half)]
#pragma unroll
      for (int ni = 0; ni < 2; ni++) {
        const int kr = (c * 32 + ni * 16 + ln) * 64;
        kf[ni][0] = *(const bf16x8*)&K_[kr + ((quad ^ (ln & 7)) * 8)];
        kf[ni][1] = *(const bf16x8*)&K_[kr + (((4 + quad) ^ (ln & 7)) * 8)];
      }

      // S^T: sacc[mi][ni][r] = S[key=c*32+ni*16+quad*4+r][m=mi*16+ln]
      f32x4 sacc[4][2];
      __builtin_amdgcn_s_setprio(1);
#pragma unroll
      for (int ni = 0; ni < 2; ni++)
#pragma unroll
        for (int mi = 0; mi < 4; mi++) {
          f32x4 tt = __builtin_amdgcn_mfma_f32_16x16x32_bf16(kf[ni][0], qf[mi][0],
                                                             fzero, 0, 0, 0);
          sacc[mi][ni] = __builtin_amdgcn_mfma_f32_16x16x32_bf16(kf[ni][1], qf[mi][1],
                                                                 tt, 0, 0, 0);
        }
      __builtin_amdgcn_s_setprio(0);

      // fixed-max softmax: p = exp2(s), packed straight into PV B-fragments.
      // pfa[mi][j]: j<4 -> exp2(sacc[mi][0][j]); j>=4 -> exp2(sacc[mi][1][j-4])
      bf16x8 pfa[4];
#pragma unroll
      for (int mi = 0; mi < 4; mi++) {
        float p0 = EXP2(sacc[mi][0][0]);
        float p1 = EXP2(sacc[mi][0][1]);
        float p2 = EXP2(sacc[mi][0][2]);
        float p3 = EXP2(sacc[mi][0][3]);
        float p4 = EXP2(sacc[mi][1][0]);
        float p5 = EXP2(sacc[mi][1][1]);
        float p6 = EXP2(sacc[mi][1][2]);
        float p7 = EXP2(sacc[mi][1][3]);
        lacc[mi] += ((p0 + p1) + (p2 + p3)) + ((p4 + p5) + (p6 + p7));
        pfa[mi][0] = (__bf16)p0; pfa[mi][1] = (__bf16)p1;
        pfa[mi][2] = (__bf16)p2; pfa[mi][3] = (__bf16)p3;
        pfa[mi][4] = (__bf16)p4; pfa[mi][5] = (__bf16)p5;
        pfa[mi][6] = (__bf16)p6; pfa[mi][7] = (__bf16)p7;
      }

      // O^T += Vt * P^T. Permuted-V chunk c*4+quad holds this lane's 8 keys
      // in exactly pfa's order.
#pragma unroll
      for (int ni = 0; ni < 4; ni++) {
        bf16x8 vf = *(const bf16x8*)
            &V_[(ni * 16 + ln) * 64 + (((4 * c + quad) ^ (ln & 7)) * 8)];
        __builtin_amdgcn_s_setprio(1);
#pragma unroll
        for (int mi = 0; mi < 4; mi++)
          oacc[ni][mi] = __builtin_amdgcn_mfma_f32_16x16x32_bf16(vf, pfa[mi],
                                                                 oacc[ni][mi], 0, 0, 0);
        __builtin_amdgcn_s_setprio(0);
      }
    }
    __syncthreads();  // drains prefetch vmcnt; all waves done reading K_/V_
  };

  STAGE(0, Kls0, Vls0);
  __syncthreads();
  for (int kt = 0; kt < 32; kt += 2) {
    BODY(kt, Kls0, Vls0, Kls1, Vls1);
    BODY(kt + 1, Kls1, Vls1, Kls0, Vls0);
  }

  // epilogue: reduce row sums across quads, then O[m][d] = O^T / lsum
#pragma unroll
  for (int mi = 0; mi < 4; mi++) {
    float ls = lacc[mi];
    ls += __shfl_xor(ls, 16);
    ls += __shfl_xor(ls, 32);
    float inv = 1.0f / ls;
    u16* Og = Out + ((size_t)b * 2048 + qt * 256 + w * 64 + mi * 16 + ln) * 1024 + h * 64;
#pragma unroll
    for (int ni = 0; ni < 4; ni++) {
      bf16x4 ov = {(__bf16)(oacc[ni][mi][0] * inv), (__bf16)(oacc[ni][mi][1] * inv),
                   (__bf16)(oacc[ni][mi][2] * inv), (__bf16)(oacc[ni][mi][3] * inv)};
      *(bf16x4*)&Og[ni * 16 + quad * 4] = ov;
    }
  }
}

// ---------------------------------------------------------------------------
extern "C" void kernel_launch(void* const* d_in, const int* in_sizes, int n_in,
                              void* d_out, int out_size, void* d_ws, size_t ws_size,
                              hipStream_t stream) {
  const float* x    = (const float*)d_in[0];
  const float* lns  = (const float*)d_in[1];
  const float* lnb  = (const float*)d_in[2];
  const float* Wq   = (const float*)d_in[3];
  const float* Wkv  = (const float*)d_in[4];
  const float* qns  = (const float*)d_in[5];
  const float* qnb  = (const float*)d_in[6];
  const float* kns  = (const float*)d_in[7];
  const float* knb  = (const float*)d_in[8];
  const float* Wout = (const float*)d_in[9];
  float* out = (float*)d_out;
  char* ws = (char*)d_ws;

  const size_t o_xn  = 0;                 // 16 MB: xn (bf16), later Qbuf
  const size_t o_qkv = 16777216;          // 24 MB: qkv (bf16), later attn_out
  const size_t o_bt  = o_qkv + 25165824;  // 3 MB: W^T (bf16), reused for Wout^T
  const size_t o_k   = o_bt + 3145728;    // 4 MB: Kbuf
  const size_t o_vt  = o_k + 4194304;     // 4 MB: Vtbuf
  u16* xn   = (u16*)(ws + o_xn);
  u16* qkv  = (u16*)(ws + o_qkv);
  u16* bt   = (u16*)(ws + o_bt);
  u16* Kbuf = (u16*)(ws + o_k);
  u16* Vtb  = (u16*)(ws + o_vt);
  u16* Qbuf = xn;    // xn dead after GEMM1
  u16* aout = qkv;   // qkv dead after qk_ln/vtrans

  transpose64<<<dim3(16, 16), 256, 0, stream>>>(Wq, bt, 1024);
  transpose64<<<dim3(16, 8), 256, 0, stream>>>(Wkv, bt + 1024 * 1024, 512);
  ln_x<<<8192, 256, 0, stream>>>(x, lns, lnb, xn);
  gemm_bt<false><<<dim3(12, 64), 256, 0, stream>>>(xn, bt, qkv, 8192, 1536, 1024);
  transpose64<<<dim3(16, 16), 256, 0, stream>>>(Wout, bt, 1024);
  qk_ln<<<8192, 256, 0, stream>>>(qkv, qns, qnb, kns, knb, Qbuf, Kbuf);
  vtrans<<<dim3(32, 16), 256, 0, stream>>>(qkv, Vtb);
  attn<<<dim3(8, 64), 256, 0, stream>>>(Qbuf, Kbuf, Vtb, aout);
  gemm_bt<true><<<dim3(8, 64), 256, 0, stream>>>(aout, bt, out, 8192, 1024, 1024);

  (void)in_sizes; (void)n_in; (void)out_size; (void)ws_size;
}

// Round 7
// 270.234 us; speedup vs baseline: 2.5460x; 2.5460x over previous
//
#include <hip/hip_runtime.h>
#include <cstdint>
#include <cstddef>

// All external tensors are FP32 (per reference). Internals use bf16 for MFMA.
typedef unsigned short u16;
typedef __attribute__((ext_vector_type(4))) float f32x4;
typedef __attribute__((ext_vector_type(8))) __bf16 bf16x8;
typedef __attribute__((ext_vector_type(4))) __bf16 bf16x4;
typedef __attribute__((ext_vector_type(8))) unsigned short u16x8;
typedef __attribute__((ext_vector_type(4))) unsigned short u16x4;

#define DEV static __device__ __forceinline__

#if __has_builtin(__builtin_amdgcn_exp2f)
#define EXP2(x) __builtin_amdgcn_exp2f(x)
#else
#define EXP2(x) exp2f(x)
#endif

DEV float bf2f(u16 v) { return __uint_as_float(((unsigned)v) << 16); }
DEV u16 f2bf(float f) {
  unsigned u = __float_as_uint(f);
  return (u16)((u + 0x7FFFu + ((u >> 16) & 1u)) >> 16);
}

DEV void gl_lds16(const void* g, void* l) {
  __builtin_amdgcn_global_load_lds((const __attribute__((address_space(1))) void*)g,
                                   (__attribute__((address_space(3))) void*)l, 16, 0, 0);
}

// ---------------------------------------------------------------------------
// 64x64 tiled transpose + fp32->bf16 cast: out[c][r] = bf16(in[r][c]).
__global__ __launch_bounds__(256) void transpose64(const float* __restrict__ in,
                                                   u16* __restrict__ out, int incols) {
  __shared__ __attribute__((aligned(16))) u16 t[64 * 72];
  const int r0 = blockIdx.x * 64, c0 = blockIdx.y * 64, tid = threadIdx.x;
#pragma unroll
  for (int i = 0; i < 2; i++) {
    int c = i * 256 + tid;
    int row = c >> 3, cc = c & 7;
    const float* src = &in[(size_t)(r0 + row) * incols + c0 + cc * 8];
    f32x4 v0 = *(const f32x4*)src;
    f32x4 v1 = *(const f32x4*)(src + 4);
    u16x8 o;
#pragma unroll
    for (int j = 0; j < 4; j++) { o[j] = f2bf(v0[j]); o[4 + j] = f2bf(v1[j]); }
    *(u16x8*)&t[row * 72 + cc * 8] = o;
  }
  __syncthreads();
#pragma unroll
  for (int i = 0; i < 2; i++) {
    int c = i * 256 + tid;
    int d = c >> 3, nc = c & 7;
    u16x8 o;
#pragma unroll
    for (int j = 0; j < 8; j++) o[j] = t[(nc * 8 + j) * 72 + d];
    *(u16x8*)&out[(size_t)(c0 + d) * 1024 + r0 + nc * 8] = o;
  }
}

// ---------------------------------------------------------------------------
// LayerNorm over DIM=1024 (fp32 in, bf16 out), one block per row.
__global__ __launch_bounds__(256) void ln_x(const float* __restrict__ x,
                                            const float* __restrict__ sc,
                                            const float* __restrict__ bi,
                                            u16* __restrict__ xn) {
  __shared__ float red[8];
  const int row = blockIdx.x, tid = threadIdx.x;
  const int w = tid >> 6;
  f32x4 f = *(const f32x4*)&x[(size_t)row * 1024 + tid * 4];
  float s = f[0] + f[1] + f[2] + f[3];
  float q = f[0] * f[0] + f[1] * f[1] + f[2] * f[2] + f[3] * f[3];
#pragma unroll
  for (int off = 1; off < 64; off <<= 1) {
    s += __shfl_xor(s, off);
    q += __shfl_xor(q, off);
  }
  if ((tid & 63) == 0) { red[w] = s; red[4 + w] = q; }
  __syncthreads();
  float S = red[0] + red[1] + red[2] + red[3];
  float Q = red[4] + red[5] + red[6] + red[7];
  float mu = S * (1.0f / 1024.0f);
  float var = Q * (1.0f / 1024.0f) - mu * mu;
  float rs = rsqrtf(var + 1e-6f);
  f32x4 scv = *(const f32x4*)&sc[tid * 4];
  f32x4 biv = *(const f32x4*)&bi[tid * 4];
  u16* o = xn + (size_t)row * 1024 + tid * 4;
#pragma unroll
  for (int j = 0; j < 4; j++) o[j] = f2bf((f[j] - mu) * rs * scv[j] + biv[j]);
}

// ---------------------------------------------------------------------------
// C[M][N] = A[M][K] * Bt[N][K]^T, bf16 in; out bf16 or fp32 (F32OUT).
// 128x128 tile, BK=64 (half the barriers of BK=32), XOR-swizzled LDS
// (logical 16B chunk c of row r lives at slot c^(r&7)) -> <=2-way conflicts.
template <bool F32OUT>
__global__ __launch_bounds__(256) void gemm_bt(const u16* __restrict__ A,
                                               const u16* __restrict__ Bt,
                                               void* __restrict__ Cp,
                                               int M, int N, int K) {
  __shared__ __attribute__((aligned(16))) u16 Als[128 * 64];
  __shared__ __attribute__((aligned(16))) u16 Bls[128 * 64];
  const int tid = threadIdx.x;
  const int w = tid >> 6, lane = tid & 63, ln = lane & 15, quad = lane >> 4;
  const int m0 = blockIdx.y * 128, n0 = blockIdx.x * 128;
  const int moff = (w & 1) * 64, noff = (w >> 1) * 64;
  const f32x4 fzero = {0.f, 0.f, 0.f, 0.f};
  f32x4 acc[4][4];
#pragma unroll
  for (int i = 0; i < 4; i++)
#pragma unroll
    for (int j = 0; j < 4; j++) acc[i][j] = fzero;

  // staging source bases: 4 chunks each for A and B per thread
  const u16* aS[4];
  const u16* bS[4];
#pragma unroll
  for (int i = 0; i < 4; i++) {
    int s = i * 256 + tid;
    int row = s >> 3, cs = (s & 7) ^ (row & 7);
    aS[i] = A + (size_t)(m0 + row) * K + cs * 8;
    bS[i] = Bt + (size_t)(n0 + row) * K + cs * 8;
  }

  for (int k0 = 0; k0 < K; k0 += 64) {
    __syncthreads();
#pragma unroll
    for (int i = 0; i < 4; i++) {
      int s = i * 256 + tid;
      gl_lds16(aS[i] + k0, &Als[s * 8]);
      gl_lds16(bS[i] + k0, &Bls[s * 8]);
    }
    __syncthreads();
#pragma unroll
    for (int kk = 0; kk < 2; kk++) {
      bf16x8 af[4], bfv[4];
#pragma unroll
      for (int mi = 0; mi < 4; mi++)
        af[mi] = *(const bf16x8*)
            &Als[(moff + mi * 16 + ln) * 64 + (((kk * 4 + quad) ^ (ln & 7)) * 8)];
#pragma unroll
      for (int ni = 0; ni < 4; ni++)
        bfv[ni] = *(const bf16x8*)
            &Bls[(noff + ni * 16 + ln) * 64 + (((kk * 4 + quad) ^ (ln & 7)) * 8)];
#pragma unroll
      for (int mi = 0; mi < 4; mi++)
#pragma unroll
        for (int ni = 0; ni < 4; ni++)
          acc[mi][ni] = __builtin_amdgcn_mfma_f32_16x16x32_bf16(af[mi], bfv[ni],
                                                                acc[mi][ni], 0, 0, 0);
    }
  }
#pragma unroll
  for (int mi = 0; mi < 4; mi++)
#pragma unroll
    for (int ni = 0; ni < 4; ni++)
#pragma unroll
      for (int r = 0; r < 4; r++) {
        size_t m = m0 + moff + mi * 16 + quad * 4 + r;
        size_t n = n0 + noff + ni * 16 + ln;
        if (F32OUT)
          ((float*)Cp)[m * N + n] = acc[mi][ni][r];
        else
          ((u16*)Cp)[m * N + n] = f2bf(acc[mi][ni][r]);
      }
}

// ---------------------------------------------------------------------------
// Per-head LN of q and k slices of qkv[8192][1536] (bf16); fp32 params.
// Q pre-scaled by 0.125*log2(e): scores directly in exp2 domain (fixed-max
// softmax is safe: LN'd q,k => |score| <= ~11.5).
__global__ __launch_bounds__(256) void qk_ln(const u16* __restrict__ qkv,
                                             const float* __restrict__ qs,
                                             const float* __restrict__ qb,
                                             const float* __restrict__ ks,
                                             const float* __restrict__ kb,
                                             u16* __restrict__ Q,
                                             u16* __restrict__ Kb) {
  const float SCL = 0.18033688011112042f;  // 0.125 * log2(e)
  const int m = blockIdx.x;
  const int b = m >> 11, n = m & 2047;
  const int tid = threadIdx.x, w = tid >> 6, lane = tid & 63;
  const u16* rowp = qkv + (size_t)m * 1536;
  const float qsc = qs[lane], qbi = qb[lane];
  const float ksc = ks[lane], kbi = kb[lane];
#pragma unroll
  for (int i = 0; i < 4; i++) {
    int h = w * 4 + i;
    float v = bf2f(rowp[h * 64 + lane]);
    float s = v, q2 = v * v;
#pragma unroll
    for (int off = 1; off < 64; off <<= 1) {
      s += __shfl_xor(s, off);
      q2 += __shfl_xor(q2, off);
    }
    float mu = s * (1.0f / 64.0f);
    float var = q2 * (1.0f / 64.0f) - mu * mu;
    float y = ((v - mu) * rsqrtf(var + 1e-6f) * qsc + qbi) * SCL;
    Q[((size_t)(b * 16 + h) * 2048 + n) * 64 + lane] = f2bf(y);
  }
  {
    int g = w;
    float v = bf2f(rowp[1024 + g * 64 + lane]);
    float s = v, q2 = v * v;
#pragma unroll
    for (int off = 1; off < 64; off <<= 1) {
      s += __shfl_xor(s, off);
      q2 += __shfl_xor(q2, off);
    }
    float mu = s * (1.0f / 64.0f);
    float var = q2 * (1.0f / 64.0f) - mu * mu;
    float y = (v - mu) * rsqrtf(var + 1e-6f) * ksc + kbi;
    Kb[((size_t)(b * 4 + g) * 2048 + n) * 64 + lane] = f2bf(y);
  }
}

// ---------------------------------------------------------------------------
// V transpose: qkv v-slice -> Vt [b][g][64][2048]. grid = (32, 16).
// Keys are PERMUTED within each 64-key tile so attn's PV A-operand is one
// contiguous 16B chunk per lane:
//   key kappa = 32c + quad*4 + u*16 + v  ->  pos p = 32c + quad*8 + u*4 + v
__global__ __launch_bounds__(256) void vtrans(const u16* __restrict__ qkv,
                                              u16* __restrict__ Vt) {
  __shared__ __attribute__((aligned(16))) u16 t[64 * 72];
  const int n0 = blockIdx.x * 64;
  const int bg = blockIdx.y;
  const int b = bg >> 2, g = bg & 3;
  const int tid = threadIdx.x;
  const u16* src = qkv + (size_t)(b * 2048 + n0) * 1536 + 1280 + g * 64;
#pragma unroll
  for (int i = 0; i < 2; i++) {
    int c = i * 256 + tid;
    int row = c >> 3, cc = c & 7;
    *(f32x4*)&t[row * 72 + cc * 8] = *(const f32x4*)&src[(size_t)row * 1536 + cc * 8];
  }
  __syncthreads();
  u16* dst = Vt + (size_t)bg * 64 * 2048 + n0;
#pragma unroll
  for (int i = 0; i < 2; i++) {
    int c = i * 256 + tid;
    int d = c >> 3, nc = c & 7;
    // keys kappa = nc*8 + j; j=0..3 land at pA+j, j=4..7 at pA+8+(j&3)
    const int pA = 32 * (nc >> 2) + (nc & 1) * 16 + ((nc >> 1) & 1) * 4;
    u16x8 o;
#pragma unroll
    for (int j = 0; j < 8; j++) o[j] = t[(nc * 8 + j) * 72 + d];
    u16x4 lo = {o[0], o[1], o[2], o[3]};
    u16x4 hi = {o[4], o[5], o[6], o[7]};
    *(u16x4*)&dst[(size_t)d * 2048 + pA] = lo;
    *(u16x4*)&dst[(size_t)d * 2048 + pA + 8] = hi;
  }
}

// ---------------------------------------------------------------------------
// Flash attention, transposed-S, fixed-max softmax, KT=64 keys/iter.
//
// Round-7 == round-6 resubmit (round-6 bench was an infra failure, not a
// kernel verdict). EXACT round-3 structure (verified 79.4us: 128-thr blocks,
// 2 waves x 64 q-rows, grid (16,64), LDS K/V dbuf, one barrier/kt, lane-local
// P, permuted-V b128 PV reads, 0 bank conflicts, launch_bounds(128,2) ->
// VGPR cap 256; round-5's (256,4)=128-cap caused a 1.4GB spill disaster).
// One change vs round-3: softmax row-sum moved off the VALU onto the matrix
// pipe via an all-ones A-operand MFMA:
//   rsum[mi] = mfma(ones, pfa[mi], rsum[mi])  => D[i][j] = sum_k P[k][j]
// Every lane's rsum[mi][r] holds the full row sum for q-row mi*16+ln (key
// order is a permutation -> sum invariant; accumulates across chunks/tiles).
// Deletes 64 VALU adds/lane/iter AND the epilogue cross-lane shuffles, costs
// 8 MFMA/iter on the less-busy matrix pipe. Denominator now sums the same
// bf16-rounded P used in PV (more consistent than before).
__global__ __launch_bounds__(128, 2) void attn(const u16* __restrict__ Q,
                                               const u16* __restrict__ Kb,
                                               const u16* __restrict__ Vt,
                                               u16* __restrict__ Out) {
  __shared__ __attribute__((aligned(16))) u16 Kls0[64 * 64];
  __shared__ __attribute__((aligned(16))) u16 Kls1[64 * 64];
  __shared__ __attribute__((aligned(16))) u16 Vls0[64 * 64];
  __shared__ __attribute__((aligned(16))) u16 Vls1[64 * 64];
  const int qt = blockIdx.x;
  const int bh = blockIdx.y;
  const int b = bh >> 4, h = bh & 15, g = h >> 2;
  const int tid = threadIdx.x, w = tid >> 6, lane = tid & 63;
  const int ln = lane & 15, quad = lane >> 4;
  const u16* Qg = Q + ((size_t)(b * 16 + h) * 2048 + qt * 128 + w * 64) * 64;
  const u16* Kg = Kb + (size_t)(b * 4 + g) * 2048 * 64;
  const u16* Vg = Vt + (size_t)(b * 4 + g) * 64 * 2048;
  const f32x4 fzero = {0.f, 0.f, 0.f, 0.f};

  // Q fragments (B-operand): rows m = mi*16+ln, k(d) = ks2*32 + quad*8
  bf16x8 qf[4][2];
#pragma unroll
  for (int mi = 0; mi < 4; mi++)
#pragma unroll
    for (int ks2 = 0; ks2 < 2; ks2++)
      qf[mi][ks2] = *(const bf16x8*)&Qg[(size_t)(mi * 16 + ln) * 64 + ks2 * 32 + quad * 8];

  f32x4 oacc[4][4];  // [ni(d-tile)][mi(m-tile)]
#pragma unroll
  for (int ni = 0; ni < 4; ni++)
#pragma unroll
    for (int mi = 0; mi < 4; mi++) oacc[ni][mi] = fzero;
  f32x4 rsum[4];  // row-sum accumulators (MFMA ones-trick)
#pragma unroll
  for (int mi = 0; mi < 4; mi++) rsum[mi] = fzero;
  bf16x8 vones;
#pragma unroll
  for (int j = 0; j < 8; j++) vones[j] = (__bf16)1.0f;

  // staging geometry: 4 K-chunks + 4 V-chunks per thread (128 threads)
  int krow[4], kcs[4];
#pragma unroll
  for (int i = 0; i < 4; i++) {
    int s = i * 128 + tid;
    krow[i] = s >> 3;
    kcs[i] = (s & 7) ^ (krow[i] & 7);
  }

  auto STAGE = [&](int kt, u16* Kd, u16* Vd) {
#pragma unroll
    for (int i = 0; i < 4; i++) {
      int s = i * 128 + tid;
      gl_lds16(Kg + (size_t)(kt * 64 + krow[i]) * 64 + kcs[i] * 8, &Kd[s * 8]);
      gl_lds16(Vg + (size_t)krow[i] * 2048 + kt * 64 + kcs[i] * 8, &Vd[s * 8]);
    }
  };

  auto BODY = [&](int kt, const u16* K_, const u16* V_, u16* Kn, u16* Vn) {
    if (kt + 1 < 32) STAGE(kt + 1, Kn, Vn);  // prefetch, in flight during compute

#pragma unroll
    for (int c = 0; c < 2; c++) {  // two 32-key chunks
      // K fragments for keys c*32 + [0,32)
      bf16x8 kf[2][2];  // [ni(key-16-tile)][kstep(d half)]
#pragma unroll
      for (int ni = 0; ni < 2; ni++) {
        const int kr = (c * 32 + ni * 16 + ln) * 64;
        kf[ni][0] = *(const bf16x8*)&K_[kr + ((quad ^ (ln & 7)) * 8)];
        kf[ni][1] = *(const bf16x8*)&K_[kr + (((4 + quad) ^ (ln & 7)) * 8)];
      }

      // S^T: sacc[mi][ni][r] = S[key=c*32+ni*16+quad*4+r][m=mi*16+ln]
      f32x4 sacc[4][2];
      __builtin_amdgcn_s_setprio(1);
#pragma unroll
      for (int ni = 0; ni < 2; ni++)
#pragma unroll
        for (int mi = 0; mi < 4; mi++) {
          f32x4 tt = __builtin_amdgcn_mfma_f32_16x16x32_bf16(kf[ni][0], qf[mi][0],
                                                             fzero, 0, 0, 0);
          sacc[mi][ni] = __builtin_amdgcn_mfma_f32_16x16x32_bf16(kf[ni][1], qf[mi][1],
                                                                 tt, 0, 0, 0);
        }
      __builtin_amdgcn_s_setprio(0);

      // fixed-max softmax: p = exp2(s), packed straight into PV B-fragments.
      // pfa[mi][j]: j<4 -> exp2(sacc[mi][0][j]); j>=4 -> exp2(sacc[mi][1][j-4])
      bf16x8 pfa[4];
#pragma unroll
      for (int mi = 0; mi < 4; mi++) {
        pfa[mi][0] = (__bf16)EXP2(sacc[mi][0][0]);
        pfa[mi][1] = (__bf16)EXP2(sacc[mi][0][1]);
        pfa[mi][2] = (__bf16)EXP2(sacc[mi][0][2]);
        pfa[mi][3] = (__bf16)EXP2(sacc[mi][0][3]);
        pfa[mi][4] = (__bf16)EXP2(sacc[mi][1][0]);
        pfa[mi][5] = (__bf16)EXP2(sacc[mi][1][1]);
        pfa[mi][6] = (__bf16)EXP2(sacc[mi][1][2]);
        pfa[mi][7] = (__bf16)EXP2(sacc[mi][1][3]);
      }

      // row sums on the matrix pipe: rsum[mi] += ones * pfa[mi]
#pragma unroll
      for (int mi = 0; mi < 4; mi++)
        rsum[mi] = __builtin_amdgcn_mfma_f32_16x16x32_bf16(vones, pfa[mi],
                                                           rsum[mi], 0, 0, 0);

      // O^T += Vt * P^T. Permuted-V chunk c*4+quad holds this lane's 8 keys
      // in exactly pfa's order.
#pragma unroll
      for (int ni = 0; ni < 4; ni++) {
        bf16x8 vf = *(const bf16x8*)
            &V_[(ni * 16 + ln) * 64 + (((4 * c + quad) ^ (ln & 7)) * 8)];
        __builtin_amdgcn_s_setprio(1);
#pragma unroll
        for (int mi = 0; mi < 4; mi++)
          oacc[ni][mi] = __builtin_amdgcn_mfma_f32_16x16x32_bf16(vf, pfa[mi],
                                                                 oacc[ni][mi], 0, 0, 0);
        __builtin_amdgcn_s_setprio(0);
      }
    }
    __syncthreads();  // drains prefetch vmcnt; all waves done reading K_/V_
  };

  STAGE(0, Kls0, Vls0);
  __syncthreads();
  for (int kt = 0; kt < 32; kt += 2) {
    BODY(kt, Kls0, Vls0, Kls1, Vls1);
    BODY(kt + 1, Kls1, Vls1, Kls0, Vls0);
  }

  // epilogue: O[m][d] = O^T / lsum; lsum = rsum[mi][0] (all lanes/regs equal
  // for a given ln -- no cross-lane reduce needed)
#pragma unroll
  for (int mi = 0; mi < 4; mi++) {
    float inv = 1.0f / rsum[mi][0];
    u16* Og = Out + ((size_t)b * 2048 + qt * 128 + w * 64 + mi * 16 + ln) * 1024 + h * 64;
#pragma unroll
    for (int ni = 0; ni < 4; ni++) {
      bf16x4 ov = {(__bf16)(oacc[ni][mi][0] * inv), (__bf16)(oacc[ni][mi][1] * inv),
                   (__bf16)(oacc[ni][mi][2] * inv), (__bf16)(oacc[ni][mi][3] * inv)};
      *(bf16x4*)&Og[ni * 16 + quad * 4] = ov;
    }
  }
}

// ---------------------------------------------------------------------------
extern "C" void kernel_launch(void* const* d_in, const int* in_sizes, int n_in,
                              void* d_out, int out_size, void* d_ws, size_t ws_size,
                              hipStream_t stream) {
  const float* x    = (const float*)d_in[0];
  const float* lns  = (const float*)d_in[1];
  const float* lnb  = (const float*)d_in[2];
  const float* Wq   = (const float*)d_in[3];
  const float* Wkv  = (const float*)d_in[4];
  const float* qns  = (const float*)d_in[5];
  const float* qnb  = (const float*)d_in[6];
  const float* kns  = (const float*)d_in[7];
  const float* knb  = (const float*)d_in[8];
  const float* Wout = (const float*)d_in[9];
  float* out = (float*)d_out;
  char* ws = (char*)d_ws;

  const size_t o_xn  = 0;                 // 16 MB: xn (bf16), later Qbuf
  const size_t o_qkv = 16777216;          // 24 MB: qkv (bf16), later attn_out
  const size_t o_bt  = o_qkv + 25165824;  // 3 MB: W^T (bf16), reused for Wout^T
  const size_t o_k   = o_bt + 3145728;    // 4 MB: Kbuf
  const size_t o_vt  = o_k + 4194304;     // 4 MB: Vtbuf
  u16* xn   = (u16*)(ws + o_xn);
  u16* qkv  = (u16*)(ws + o_qkv);
  u16* bt   = (u16*)(ws + o_bt);
  u16* Kbuf = (u16*)(ws + o_k);
  u16* Vtb  = (u16*)(ws + o_vt);
  u16* Qbuf = xn;    // xn dead after GEMM1
  u16* aout = qkv;   // qkv dead after qk_ln/vtrans

  transpose64<<<dim3(16, 16), 256, 0, stream>>>(Wq, bt, 1024);
  transpose64<<<dim3(16, 8), 256, 0, stream>>>(Wkv, bt + 1024 * 1024, 512);
  ln_x<<<8192, 256, 0, stream>>>(x, lns, lnb, xn);
  gemm_bt<false><<<dim3(12, 64), 256, 0, stream>>>(xn, bt, qkv, 8192, 1536, 1024);
  transpose64<<<dim3(16, 16), 256, 0, stream>>>(Wout, bt, 1024);
  qk_ln<<<8192, 256, 0, stream>>>(qkv, qns, qnb, kns, knb, Qbuf, Kbuf);
  vtrans<<<dim3(32, 16), 256, 0, stream>>>(qkv, Vtb);
  attn<<<dim3(16, 64), 128, 0, stream>>>(Qbuf, Kbuf, Vtb, aout);
  gemm_bt<true><<<dim3(8, 64), 256, 0, stream>>>(aout, bt, out, 8192, 1024, 1024);

  (void)in_sizes; (void)n_in; (void)out_size; (void)ws_size;
}

// Round 8
// 248.443 us; speedup vs baseline: 2.7693x; 1.0877x over previous
//
#include <hip/hip_runtime.h>
#include <cstdint>
#include <cstddef>

// All external tensors are FP32 (per reference). Internals use bf16 for MFMA.
typedef unsigned short u16;
typedef __attribute__((ext_vector_type(4))) float f32x4;
typedef __attribute__((ext_vector_type(8))) __bf16 bf16x8;
typedef __attribute__((ext_vector_type(4))) __bf16 bf16x4;
typedef __attribute__((ext_vector_type(8))) unsigned short u16x8;
typedef __attribute__((ext_vector_type(4))) unsigned short u16x4;

#define DEV static __device__ __forceinline__

#if __has_builtin(__builtin_amdgcn_exp2f)
#define EXP2(x) __builtin_amdgcn_exp2f(x)
#else
#define EXP2(x) exp2f(x)
#endif

DEV float bf2f(u16 v) { return __uint_as_float(((unsigned)v) << 16); }
DEV u16 f2bf(float f) {
  unsigned u = __float_as_uint(f);
  return (u16)((u + 0x7FFFu + ((u >> 16) & 1u)) >> 16);
}

DEV void gl_lds16(const void* g, void* l) {
  __builtin_amdgcn_global_load_lds((const __attribute__((address_space(1))) void*)g,
                                   (__attribute__((address_space(3))) void*)l, 16, 0, 0);
}

// ---------------------------------------------------------------------------
// 64x64 tiled transpose + fp32->bf16 cast: out[c][r] = bf16(in[r][c]).
__global__ __launch_bounds__(256) void transpose64(const float* __restrict__ in,
                                                   u16* __restrict__ out, int incols) {
  __shared__ __attribute__((aligned(16))) u16 t[64 * 72];
  const int r0 = blockIdx.x * 64, c0 = blockIdx.y * 64, tid = threadIdx.x;
#pragma unroll
  for (int i = 0; i < 2; i++) {
    int c = i * 256 + tid;
    int row = c >> 3, cc = c & 7;
    const float* src = &in[(size_t)(r0 + row) * incols + c0 + cc * 8];
    f32x4 v0 = *(const f32x4*)src;
    f32x4 v1 = *(const f32x4*)(src + 4);
    u16x8 o;
#pragma unroll
    for (int j = 0; j < 4; j++) { o[j] = f2bf(v0[j]); o[4 + j] = f2bf(v1[j]); }
    *(u16x8*)&t[row * 72 + cc * 8] = o;
  }
  __syncthreads();
#pragma unroll
  for (int i = 0; i < 2; i++) {
    int c = i * 256 + tid;
    int d = c >> 3, nc = c & 7;
    u16x8 o;
#pragma unroll
    for (int j = 0; j < 8; j++) o[j] = t[(nc * 8 + j) * 72 + d];
    *(u16x8*)&out[(size_t)(c0 + d) * 1024 + r0 + nc * 8] = o;
  }
}

// ---------------------------------------------------------------------------
// LayerNorm over DIM=1024 (fp32 in, bf16 out), one block per row.
__global__ __launch_bounds__(256) void ln_x(const float* __restrict__ x,
                                            const float* __restrict__ sc,
                                            const float* __restrict__ bi,
                                            u16* __restrict__ xn) {
  __shared__ float red[8];
  const int row = blockIdx.x, tid = threadIdx.x;
  const int w = tid >> 6;
  f32x4 f = *(const f32x4*)&x[(size_t)row * 1024 + tid * 4];
  float s = f[0] + f[1] + f[2] + f[3];
  float q = f[0] * f[0] + f[1] * f[1] + f[2] * f[2] + f[3] * f[3];
#pragma unroll
  for (int off = 1; off < 64; off <<= 1) {
    s += __shfl_xor(s, off);
    q += __shfl_xor(q, off);
  }
  if ((tid & 63) == 0) { red[w] = s; red[4 + w] = q; }
  __syncthreads();
  float S = red[0] + red[1] + red[2] + red[3];
  float Q = red[4] + red[5] + red[6] + red[7];
  float mu = S * (1.0f / 1024.0f);
  float var = Q * (1.0f / 1024.0f) - mu * mu;
  float rs = rsqrtf(var + 1e-6f);
  f32x4 scv = *(const f32x4*)&sc[tid * 4];
  f32x4 biv = *(const f32x4*)&bi[tid * 4];
  u16* o = xn + (size_t)row * 1024 + tid * 4;
#pragma unroll
  for (int j = 0; j < 4; j++) o[j] = f2bf((f[j] - mu) * rs * scv[j] + biv[j]);
}

// ---------------------------------------------------------------------------
// C[M][N] = A[M][K] * Bt[N][K]^T, bf16 in; out bf16 or fp32 (F32OUT).
// 128x128 tile, BK=64, XOR-swizzled LDS -> <=2-way conflicts.
template <bool F32OUT>
__global__ __launch_bounds__(256) void gemm_bt(const u16* __restrict__ A,
                                               const u16* __restrict__ Bt,
                                               void* __restrict__ Cp,
                                               int M, int N, int K) {
  __shared__ __attribute__((aligned(16))) u16 Als[128 * 64];
  __shared__ __attribute__((aligned(16))) u16 Bls[128 * 64];
  const int tid = threadIdx.x;
  const int w = tid >> 6, lane = tid & 63, ln = lane & 15, quad = lane >> 4;
  const int m0 = blockIdx.y * 128, n0 = blockIdx.x * 128;
  const int moff = (w & 1) * 64, noff = (w >> 1) * 64;
  const f32x4 fzero = {0.f, 0.f, 0.f, 0.f};
  f32x4 acc[4][4];
#pragma unroll
  for (int i = 0; i < 4; i++)
#pragma unroll
    for (int j = 0; j < 4; j++) acc[i][j] = fzero;

  const u16* aS[4];
  const u16* bS[4];
#pragma unroll
  for (int i = 0; i < 4; i++) {
    int s = i * 256 + tid;
    int row = s >> 3, cs = (s & 7) ^ (row & 7);
    aS[i] = A + (size_t)(m0 + row) * K + cs * 8;
    bS[i] = Bt + (size_t)(n0 + row) * K + cs * 8;
  }

  for (int k0 = 0; k0 < K; k0 += 64) {
    __syncthreads();
#pragma unroll
    for (int i = 0; i < 4; i++) {
      int s = i * 256 + tid;
      gl_lds16(aS[i] + k0, &Als[s * 8]);
      gl_lds16(bS[i] + k0, &Bls[s * 8]);
    }
    __syncthreads();
#pragma unroll
    for (int kk = 0; kk < 2; kk++) {
      bf16x8 af[4], bfv[4];
#pragma unroll
      for (int mi = 0; mi < 4; mi++)
        af[mi] = *(const bf16x8*)
            &Als[(moff + mi * 16 + ln) * 64 + (((kk * 4 + quad) ^ (ln & 7)) * 8)];
#pragma unroll
      for (int ni = 0; ni < 4; ni++)
        bfv[ni] = *(const bf16x8*)
            &Bls[(noff + ni * 16 + ln) * 64 + (((kk * 4 + quad) ^ (ln & 7)) * 8)];
#pragma unroll
      for (int mi = 0; mi < 4; mi++)
#pragma unroll
        for (int ni = 0; ni < 4; ni++)
          acc[mi][ni] = __builtin_amdgcn_mfma_f32_16x16x32_bf16(af[mi], bfv[ni],
                                                                acc[mi][ni], 0, 0, 0);
    }
  }
#pragma unroll
  for (int mi = 0; mi < 4; mi++)
#pragma unroll
    for (int ni = 0; ni < 4; ni++)
#pragma unroll
      for (int r = 0; r < 4; r++) {
        size_t m = m0 + moff + mi * 16 + quad * 4 + r;
        size_t n = n0 + noff + ni * 16 + ln;
        if (F32OUT)
          ((float*)Cp)[m * N + n] = acc[mi][ni][r];
        else
          ((u16*)Cp)[m * N + n] = f2bf(acc[mi][ni][r]);
      }
}

// ---------------------------------------------------------------------------
// Round-8: QKV GEMM with FUSED per-head LayerNorm epilogue (replaces the
// separate qk_ln kernel). M=8192, N=1536, K=1024 fixed. Main loop identical
// to gemm_bt. Geometry: each wave's 64-col slice (nb = n0+noff) is exactly
// one head's d=64; for a fixed output row, a quad's 16 lanes hold all 64
// d-values (d = ni*16+ln) -> LN stats via 4 shfl_xor (width-16) per
// quantity, computed on f32 accumulators (more accurate than the old
// bf16 round-trip). Columns: [0,1024) Q-heads (LN + SCL -> Q layout),
// [1024,1280) K-groups (LN -> Kb layout), [1280,1536) V (raw bf16 ->
// compact Vraw[8192][256], transposed later by vtrans). Blocks never mix
// sections (128-wide tiles, 256-aligned section boundaries).
__global__ __launch_bounds__(256) void gemm_qkv(const u16* __restrict__ A,
                                                const u16* __restrict__ Bt,
                                                const float* __restrict__ qs,
                                                const float* __restrict__ qb,
                                                const float* __restrict__ ks,
                                                const float* __restrict__ kb,
                                                u16* __restrict__ Qout,
                                                u16* __restrict__ Kout,
                                                u16* __restrict__ Vraw) {
  const int M = 8192, N = 1536, K = 1024;
  (void)M; (void)N;
  __shared__ __attribute__((aligned(16))) u16 Als[128 * 64];
  __shared__ __attribute__((aligned(16))) u16 Bls[128 * 64];
  const int tid = threadIdx.x;
  const int w = tid >> 6, lane = tid & 63, ln = lane & 15, quad = lane >> 4;
  const int m0 = blockIdx.y * 128, n0 = blockIdx.x * 128;
  const int moff = (w & 1) * 64, noff = (w >> 1) * 64;
  const f32x4 fzero = {0.f, 0.f, 0.f, 0.f};
  f32x4 acc[4][4];
#pragma unroll
  for (int i = 0; i < 4; i++)
#pragma unroll
    for (int j = 0; j < 4; j++) acc[i][j] = fzero;

  const u16* aS[4];
  const u16* bS[4];
#pragma unroll
  for (int i = 0; i < 4; i++) {
    int s = i * 256 + tid;
    int row = s >> 3, cs = (s & 7) ^ (row & 7);
    aS[i] = A + (size_t)(m0 + row) * K + cs * 8;
    bS[i] = Bt + (size_t)(n0 + row) * K + cs * 8;
  }

  for (int k0 = 0; k0 < K; k0 += 64) {
    __syncthreads();
#pragma unroll
    for (int i = 0; i < 4; i++) {
      int s = i * 256 + tid;
      gl_lds16(aS[i] + k0, &Als[s * 8]);
      gl_lds16(bS[i] + k0, &Bls[s * 8]);
    }
    __syncthreads();
#pragma unroll
    for (int kk = 0; kk < 2; kk++) {
      bf16x8 af[4], bfv[4];
#pragma unroll
      for (int mi = 0; mi < 4; mi++)
        af[mi] = *(const bf16x8*)
            &Als[(moff + mi * 16 + ln) * 64 + (((kk * 4 + quad) ^ (ln & 7)) * 8)];
#pragma unroll
      for (int ni = 0; ni < 4; ni++)
        bfv[ni] = *(const bf16x8*)
            &Bls[(noff + ni * 16 + ln) * 64 + (((kk * 4 + quad) ^ (ln & 7)) * 8)];
#pragma unroll
      for (int mi = 0; mi < 4; mi++)
#pragma unroll
        for (int ni = 0; ni < 4; ni++)
          acc[mi][ni] = __builtin_amdgcn_mfma_f32_16x16x32_bf16(af[mi], bfv[ni],
                                                                acc[mi][ni], 0, 0, 0);
    }
  }

  // -------- fused epilogue --------
  const int nb = n0 + noff;  // 64-aligned head/group slice base (wave-uniform)
  if (nb < 1280) {
    // Q or K slice: per-row LN over d=64 (quad's 16 lanes hold all d).
    const float SCL = 0.18033688011112042f;  // 0.125 * log2(e)
    const bool isQ = (nb < 1024);
    const float* scp = isQ ? qs : ks;
    const float* bip = isQ ? qb : kb;
    const float mul = isQ ? SCL : 1.0f;
    float scl[4], bia[4];
#pragma unroll
    for (int ni = 0; ni < 4; ni++) {
      scl[ni] = scp[ni * 16 + ln];
      bia[ni] = bip[ni * 16 + ln];
    }
#pragma unroll
    for (int mi = 0; mi < 4; mi++)
#pragma unroll
      for (int r = 0; r < 4; r++) {
        const int m = m0 + moff + mi * 16 + quad * 4 + r;
        const int bidx = m >> 11, nseq = m & 2047;
        float v0 = acc[mi][0][r], v1 = acc[mi][1][r];
        float v2 = acc[mi][2][r], v3 = acc[mi][3][r];
        float s = (v0 + v1) + (v2 + v3);
        float q2 = (v0 * v0 + v1 * v1) + (v2 * v2 + v3 * v3);
#pragma unroll
        for (int off = 1; off < 16; off <<= 1) {
          s += __shfl_xor(s, off);
          q2 += __shfl_xor(q2, off);
        }
        const float mu = s * (1.0f / 64.0f);
        const float var = q2 * (1.0f / 64.0f) - mu * mu;
        const float rs = rsqrtf(var + 1e-6f);
        u16* op;
        if (isQ) {
          const int h = nb >> 6;
          op = Qout + ((size_t)(bidx * 16 + h) * 2048 + nseq) * 64;
        } else {
          const int g = (nb - 1024) >> 6;
          op = Kout + ((size_t)(bidx * 4 + g) * 2048 + nseq) * 64;
        }
        op[0 * 16 + ln] = f2bf(((v0 - mu) * rs * scl[0] + bia[0]) * mul);
        op[1 * 16 + ln] = f2bf(((v1 - mu) * rs * scl[1] + bia[1]) * mul);
        op[2 * 16 + ln] = f2bf(((v2 - mu) * rs * scl[2] + bia[2]) * mul);
        op[3 * 16 + ln] = f2bf(((v3 - mu) * rs * scl[3] + bia[3]) * mul);
      }
  } else {
    // V slice: raw bf16 into compact Vraw[8192][256]
    const int g2 = nb - 1280;  // 0,64,128,192
#pragma unroll
    for (int mi = 0; mi < 4; mi++)
#pragma unroll
      for (int r = 0; r < 4; r++) {
        const int m = m0 + moff + mi * 16 + quad * 4 + r;
        u16* op = Vraw + (size_t)m * 256 + g2;
#pragma unroll
        for (int ni = 0; ni < 4; ni++) op[ni * 16 + ln] = f2bf(acc[mi][ni][r]);
      }
  }
}

// ---------------------------------------------------------------------------
// V transpose: Vraw[8192][256] -> Vt [b][g][64][2048]. grid = (32, 16).
// Keys are PERMUTED within each 64-key tile so attn's PV A-operand is one
// contiguous 16B chunk per lane:
//   key kappa = 32c + quad*4 + u*16 + v  ->  pos p = 32c + quad*8 + u*4 + v
__global__ __launch_bounds__(256) void vtrans(const u16* __restrict__ Vraw,
                                              u16* __restrict__ Vt) {
  __shared__ __attribute__((aligned(16))) u16 t[64 * 72];
  const int n0 = blockIdx.x * 64;
  const int bg = blockIdx.y;
  const int b = bg >> 2, g = bg & 3;
  const int tid = threadIdx.x;
  const u16* src = Vraw + (size_t)(b * 2048 + n0) * 256 + g * 64;
#pragma unroll
  for (int i = 0; i < 2; i++) {
    int c = i * 256 + tid;
    int row = c >> 3, cc = c & 7;
    *(f32x4*)&t[row * 72 + cc * 8] = *(const f32x4*)&src[(size_t)row * 256 + cc * 8];
  }
  __syncthreads();
  u16* dst = Vt + (size_t)bg * 64 * 2048 + n0;
#pragma unroll
  for (int i = 0; i < 2; i++) {
    int c = i * 256 + tid;
    int d = c >> 3, nc = c & 7;
    // keys kappa = nc*8 + j; j=0..3 land at pA+j, j=4..7 at pA+8+(j&3)
    const int pA = 32 * (nc >> 2) + (nc & 1) * 16 + ((nc >> 1) & 1) * 4;
    u16x8 o;
#pragma unroll
    for (int j = 0; j < 8; j++) o[j] = t[(nc * 8 + j) * 72 + d];
    u16x4 lo = {o[0], o[1], o[2], o[3]};
    u16x4 hi = {o[4], o[5], o[6], o[7]};
    *(u16x4*)&dst[(size_t)d * 2048 + pA] = lo;
    *(u16x4*)&dst[(size_t)d * 2048 + pA + 8] = hi;
  }
}

// ---------------------------------------------------------------------------
// Flash attention, transposed-S, fixed-max softmax, KT=64 keys/iter.
// Round-7 verified 76.5us: 128-thr blocks, 2 waves x 64 q-rows, grid (16,64),
// LDS K/V dbuf, one barrier/kt, lane-local P, permuted-V b128 PV reads,
// 0 bank conflicts, rsum via all-ones MFMA, launch_bounds(128,2). UNCHANGED.
__global__ __launch_bounds__(128, 2) void attn(const u16* __restrict__ Q,
                                               const u16* __restrict__ Kb,
                                               const u16* __restrict__ Vt,
                                               u16* __restrict__ Out) {
  __shared__ __attribute__((aligned(16))) u16 Kls0[64 * 64];
  __shared__ __attribute__((aligned(16))) u16 Kls1[64 * 64];
  __shared__ __attribute__((aligned(16))) u16 Vls0[64 * 64];
  __shared__ __attribute__((aligned(16))) u16 Vls1[64 * 64];
  const int qt = blockIdx.x;
  const int bh = blockIdx.y;
  const int b = bh >> 4, h = bh & 15, g = h >> 2;
  const int tid = threadIdx.x, w = tid >> 6, lane = tid & 63;
  const int ln = lane & 15, quad = lane >> 4;
  const u16* Qg = Q + ((size_t)(b * 16 + h) * 2048 + qt * 128 + w * 64) * 64;
  const u16* Kg = Kb + (size_t)(b * 4 + g) * 2048 * 64;
  const u16* Vg = Vt + (size_t)(b * 4 + g) * 64 * 2048;
  const f32x4 fzero = {0.f, 0.f, 0.f, 0.f};

  bf16x8 qf[4][2];
#pragma unroll
  for (int mi = 0; mi < 4; mi++)
#pragma unroll
    for (int ks2 = 0; ks2 < 2; ks2++)
      qf[mi][ks2] = *(const bf16x8*)&Qg[(size_t)(mi * 16 + ln) * 64 + ks2 * 32 + quad * 8];

  f32x4 oacc[4][4];
#pragma unroll
  for (int ni = 0; ni < 4; ni++)
#pragma unroll
    for (int mi = 0; mi < 4; mi++) oacc[ni][mi] = fzero;
  f32x4 rsum[4];
#pragma unroll
  for (int mi = 0; mi < 4; mi++) rsum[mi] = fzero;
  bf16x8 vones;
#pragma unroll
  for (int j = 0; j < 8; j++) vones[j] = (__bf16)1.0f;

  int krow[4], kcs[4];
#pragma unroll
  for (int i = 0; i < 4; i++) {
    int s = i * 128 + tid;
    krow[i] = s >> 3;
    kcs[i] = (s & 7) ^ (krow[i] & 7);
  }

  auto STAGE = [&](int kt, u16* Kd, u16* Vd) {
#pragma unroll
    for (int i = 0; i < 4; i++) {
      int s = i * 128 + tid;
      gl_lds16(Kg + (size_t)(kt * 64 + krow[i]) * 64 + kcs[i] * 8, &Kd[s * 8]);
      gl_lds16(Vg + (size_t)krow[i] * 2048 + kt * 64 + kcs[i] * 8, &Vd[s * 8]);
    }
  };

  auto BODY = [&](int kt, const u16* K_, const u16* V_, u16* Kn, u16* Vn) {
    if (kt + 1 < 32) STAGE(kt + 1, Kn, Vn);

#pragma unroll
    for (int c = 0; c < 2; c++) {
      bf16x8 kf[2][2];
#pragma unroll
      for (int ni = 0; ni < 2; ni++) {
        const int kr = (c * 32 + ni * 16 + ln) * 64;
        kf[ni][0] = *(const bf16x8*)&K_[kr + ((quad ^ (ln & 7)) * 8)];
        kf[ni][1] = *(const bf16x8*)&K_[kr + (((4 + quad) ^ (ln & 7)) * 8)];
      }

      f32x4 sacc[4][2];
      __builtin_amdgcn_s_setprio(1);
#pragma unroll
      for (int ni = 0; ni < 2; ni++)
#pragma unroll
        for (int mi = 0; mi < 4; mi++) {
          f32x4 tt = __builtin_amdgcn_mfma_f32_16x16x32_bf16(kf[ni][0], qf[mi][0],
                                                             fzero, 0, 0, 0);
          sacc[mi][ni] = __builtin_amdgcn_mfma_f32_16x16x32_bf16(kf[ni][1], qf[mi][1],
                                                                 tt, 0, 0, 0);
        }
      __builtin_amdgcn_s_setprio(0);

      bf16x8 pfa[4];
#pragma unroll
      for (int mi = 0; mi < 4; mi++) {
        pfa[mi][0] = (__bf16)EXP2(sacc[mi][0][0]);
        pfa[mi][1] = (__bf16)EXP2(sacc[mi][0][1]);
        pfa[mi][2] = (__bf16)EXP2(sacc[mi][0][2]);
        pfa[mi][3] = (__bf16)EXP2(sacc[mi][0][3]);
        pfa[mi][4] = (__bf16)EXP2(sacc[mi][1][0]);
        pfa[mi][5] = (__bf16)EXP2(sacc[mi][1][1]);
        pfa[mi][6] = (__bf16)EXP2(sacc[mi][1][2]);
        pfa[mi][7] = (__bf16)EXP2(sacc[mi][1][3]);
      }

#pragma unroll
      for (int mi = 0; mi < 4; mi++)
        rsum[mi] = __builtin_amdgcn_mfma_f32_16x16x32_bf16(vones, pfa[mi],
                                                           rsum[mi], 0, 0, 0);

#pragma unroll
      for (int ni = 0; ni < 4; ni++) {
        bf16x8 vf = *(const bf16x8*)
            &V_[(ni * 16 + ln) * 64 + (((4 * c + quad) ^ (ln & 7)) * 8)];
        __builtin_amdgcn_s_setprio(1);
#pragma unroll
        for (int mi = 0; mi < 4; mi++)
          oacc[ni][mi] = __builtin_amdgcn_mfma_f32_16x16x32_bf16(vf, pfa[mi],
                                                                 oacc[ni][mi], 0, 0, 0);
        __builtin_amdgcn_s_setprio(0);
      }
    }
    __syncthreads();
  };

  STAGE(0, Kls0, Vls0);
  __syncthreads();
  for (int kt = 0; kt < 32; kt += 2) {
    BODY(kt, Kls0, Vls0, Kls1, Vls1);
    BODY(kt + 1, Kls1, Vls1, Kls0, Vls0);
  }

#pragma unroll
  for (int mi = 0; mi < 4; mi++) {
    float inv = 1.0f / rsum[mi][0];
    u16* Og = Out + ((size_t)b * 2048 + qt * 128 + w * 64 + mi * 16 + ln) * 1024 + h * 64;
#pragma unroll
    for (int ni = 0; ni < 4; ni++) {
      bf16x4 ov = {(__bf16)(oacc[ni][mi][0] * inv), (__bf16)(oacc[ni][mi][1] * inv),
                   (__bf16)(oacc[ni][mi][2] * inv), (__bf16)(oacc[ni][mi][3] * inv)};
      *(bf16x4*)&Og[ni * 16 + quad * 4] = ov;
    }
  }
}

// ---------------------------------------------------------------------------
extern "C" void kernel_launch(void* const* d_in, const int* in_sizes, int n_in,
                              void* d_out, int out_size, void* d_ws, size_t ws_size,
                              hipStream_t stream) {
  const float* x    = (const float*)d_in[0];
  const float* lns  = (const float*)d_in[1];
  const float* lnb  = (const float*)d_in[2];
  const float* Wq   = (const float*)d_in[3];
  const float* Wkv  = (const float*)d_in[4];
  const float* qns  = (const float*)d_in[5];
  const float* qnb  = (const float*)d_in[6];
  const float* kns  = (const float*)d_in[7];
  const float* knb  = (const float*)d_in[8];
  const float* Wout = (const float*)d_in[9];
  float* out = (float*)d_out;
  char* ws = (char*)d_ws;

  // Workspace map (47 MB total, was 51):
  const size_t o_xn = 0;                   // 16 MB: xn (bf16); later aout (exact fit)
  const size_t o_q  = 16777216;            // 16 MB: Q [b][h][n][d]
  const size_t o_vr = o_q + 16777216;      // 4 MB: Vraw [8192][256]
  const size_t o_bt = o_vr + 4194304;      // 3 MB: W^T (bf16), reused for Wout^T
  const size_t o_k  = o_bt + 3145728;      // 4 MB: Kbuf [b][g][n][d]
  const size_t o_vt = o_k + 4194304;       // 4 MB: Vt [b][g][d][n] (key-permuted)
  u16* xn   = (u16*)(ws + o_xn);
  u16* Qbuf = (u16*)(ws + o_q);
  u16* Vraw = (u16*)(ws + o_vr);
  u16* bt   = (u16*)(ws + o_bt);
  u16* Kbuf = (u16*)(ws + o_k);
  u16* Vtb  = (u16*)(ws + o_vt);
  u16* aout = xn;  // xn dead after gemm_qkv; attn output fits exactly (16 MiB)

  transpose64<<<dim3(16, 16), 256, 0, stream>>>(Wq, bt, 1024);
  transpose64<<<dim3(16, 8), 256, 0, stream>>>(Wkv, bt + 1024 * 1024, 512);
  ln_x<<<8192, 256, 0, stream>>>(x, lns, lnb, xn);
  gemm_qkv<<<dim3(12, 64), 256, 0, stream>>>(xn, bt, qns, qnb, kns, knb,
                                             Qbuf, Kbuf, Vraw);
  transpose64<<<dim3(16, 16), 256, 0, stream>>>(Wout, bt, 1024);
  vtrans<<<dim3(32, 16), 256, 0, stream>>>(Vraw, Vtb);
  attn<<<dim3(16, 64), 128, 0, stream>>>(Qbuf, Kbuf, Vtb, aout);
  gemm_bt<true><<<dim3(8, 64), 256, 0, stream>>>(aout, bt, out, 8192, 1024, 1024);

  (void)in_sizes; (void)n_in; (void)out_size; (void)ws_size;
}